// Round 1
// baseline (812.717 us; speedup 1.0000x reference)
//
#include <hip/hip_runtime.h>
#include <stdint.h>

#define B_  8
#define L_  512
#define Dk  256
#define O_  64
#define DP  257
#define IP  264                 // padded i-dim
#define N1  (O_ * IP)           // 16896
#define M1  (B_ * L_)           // 4096

typedef __attribute__((ext_vector_type(8))) short bf16x8;
typedef __attribute__((ext_vector_type(4))) float f32x4;

__device__ __forceinline__ unsigned short f2bf(float f) {
    union { float f; unsigned u; } v; v.f = f;
    return (unsigned short)((v.u + 0x7fffu + ((v.u >> 16) & 1u)) >> 16);
}
__device__ __forceinline__ float bf2f(unsigned short h) {
    union { unsigned u; float f; } v; v.u = ((unsigned)h) << 16;
    return v.f;
}
__device__ __forceinline__ void gload16(const void* g, void* l) {
    __builtin_amdgcn_global_load_lds(
        (const __attribute__((address_space(1))) unsigned int*)g,
        (__attribute__((address_space(3))) unsigned int*)l, 16, 0, 0);
}

// ---- convert x1, x2 (fp32 -> bf16), 4 elems/thread ----
__global__ void cvt_x(const float* __restrict__ x1, const float* __restrict__ x2,
                      unsigned short* __restrict__ x1b, unsigned short* __restrict__ x2b) {
    int idx = blockIdx.x * 256 + threadIdx.x;        // 0 .. 524287
    const int half = (M1 * Dk) / 4;                  // 262144 groups per tensor
    const float4* src; unsigned short* dst; int g;
    if (idx < half) { src = (const float4*)x1; dst = x1b; g = idx; }
    else            { src = (const float4*)x2; dst = x2b; g = idx - half; }
    float4 v = src[g];
    ushort4 w; w.x = f2bf(v.x); w.y = f2bf(v.y); w.z = f2bf(v.z); w.w = f2bf(v.w);
    *(ushort4*)&dst[g * 4] = w;
}

// ---- convert U -> W2 (bf16, rows r=o*264+i, K=256) + Ubias (fp32, j=256 col) ----
__global__ void cvt_u(const float* __restrict__ U, unsigned short* __restrict__ W2,
                      float* __restrict__ Ubias) {
    int t = blockIdx.x * 256 + threadIdx.x;          // N1*64 threads
    int r = t >> 6; int j4 = (t & 63) << 2;
    int o = r / IP, i = r % IP;
    ushort4 w;
    if (i < DP) {
        const float* up = U + ((size_t)o * DP + i) * DP + j4;
        w.x = f2bf(up[0]); w.y = f2bf(up[1]); w.z = f2bf(up[2]); w.w = f2bf(up[3]);
        if (j4 == 0) Ubias[r] = U[((size_t)o * DP + i) * DP + 256];
    } else {
        w.x = w.y = w.z = w.w = 0;
        if (j4 == 0) Ubias[r] = 0.f;
    }
    *(ushort4*)&W2[(size_t)r * Dk + j4] = w;
}

// ---- stage 1: T[4096 x 16896] = x1b[4096 x 256] @ W2[16896 x 256]^T + Ubias ----
__launch_bounds__(256)
__global__ void gemm1(const unsigned short* __restrict__ A,
                      const unsigned short* __restrict__ Bw,
                      const float* __restrict__ bias,
                      unsigned short* __restrict__ C) {
    __shared__ __align__(16) unsigned short As[128 * 32];
    __shared__ __align__(16) unsigned short Bs[128 * 32];
    const int tid = threadIdx.x, wave = tid >> 6, lane = tid & 63;
    const int m0 = blockIdx.y * 128, n0 = blockIdx.x * 128;
    const int wm = (wave >> 1) * 64, wn = (wave & 1) * 64;
    const int lrow = lane & 15, lq = lane >> 4;

    f32x4 acc[4][4] = {};
    for (int k0 = 0; k0 < Dk; k0 += 32) {
#pragma unroll
        for (int p = 0; p < 2; ++p) {
            int c = p * 256 + wave * 64 + lane;
            gload16(A  + (size_t)(m0 + (c >> 2)) * Dk + k0 + ((c & 3) << 3),
                    &As[(p * 256 + wave * 64) * 8]);
            gload16(Bw + (size_t)(n0 + (c >> 2)) * Dk + k0 + ((c & 3) << 3),
                    &Bs[(p * 256 + wave * 64) * 8]);
        }
        __syncthreads();
        bf16x8 af[4], bfr[4];
#pragma unroll
        for (int mt = 0; mt < 4; ++mt)
            af[mt] = *(const bf16x8*)&As[(wm + mt * 16 + lrow) * 32 + lq * 8];
#pragma unroll
        for (int nt = 0; nt < 4; ++nt)
            bfr[nt] = *(const bf16x8*)&Bs[(wn + nt * 16 + lrow) * 32 + lq * 8];
#pragma unroll
        for (int mt = 0; mt < 4; ++mt)
#pragma unroll
            for (int nt = 0; nt < 4; ++nt)
                acc[mt][nt] = __builtin_amdgcn_mfma_f32_16x16x32_bf16(
                    af[mt], bfr[nt], acc[mt][nt], 0, 0, 0);
        __syncthreads();
    }
#pragma unroll
    for (int mt = 0; mt < 4; ++mt)
#pragma unroll
        for (int nt = 0; nt < 4; ++nt) {
            int n = n0 + wn + nt * 16 + lrow;
            float bv = bias[n];
#pragma unroll
            for (int r = 0; r < 4; ++r) {
                int m = m0 + wm + mt * 16 + lq * 4 + r;
                C[(size_t)m * N1 + n] = f2bf(acc[mt][nt][r] + bv);
            }
        }
}

// ---- stage 2: per (b,l): out[512 x 64] = x2b[b][512 x 256] @ T[b,l][64 x 256]^T + tbias ----
__launch_bounds__(256)
__global__ void gemm2(const unsigned short* __restrict__ X2b,
                      const unsigned short* __restrict__ T,
                      float* __restrict__ out) {
    __shared__ __align__(16) unsigned short As[128 * 32];
    __shared__ __align__(16) unsigned short Bs[64 * 32];
    const int tid = threadIdx.x, wave = tid >> 6, lane = tid & 63;
    const int bl = blockIdx.y;
    const int b  = bl >> 9;
    const int m0 = blockIdx.x * 128;
    const unsigned short* Ap = X2b + (size_t)b * (L_ * Dk);
    const unsigned short* Tp = T + (size_t)bl * N1;
    const int wm = (wave >> 1) * 64, wn = (wave & 1) * 32;
    const int lrow = lane & 15, lq = lane >> 4;

    f32x4 acc[4][2] = {};
    for (int k0 = 0; k0 < Dk; k0 += 32) {
#pragma unroll
        for (int p = 0; p < 2; ++p) {
            int c = p * 256 + wave * 64 + lane;
            gload16(Ap + (size_t)(m0 + (c >> 2)) * Dk + k0 + ((c & 3) << 3),
                    &As[(p * 256 + wave * 64) * 8]);
        }
        {
            int c = wave * 64 + lane;                 // 0..255 -> o=c>>2, kc=c&3
            gload16(Tp + (size_t)(c >> 2) * IP + k0 + ((c & 3) << 3),
                    &Bs[(wave * 64) * 8]);
        }
        __syncthreads();
        bf16x8 af[4], bfr[2];
#pragma unroll
        for (int mt = 0; mt < 4; ++mt)
            af[mt] = *(const bf16x8*)&As[(wm + mt * 16 + lrow) * 32 + lq * 8];
#pragma unroll
        for (int nt = 0; nt < 2; ++nt)
            bfr[nt] = *(const bf16x8*)&Bs[(wn + nt * 16 + lrow) * 32 + lq * 8];
#pragma unroll
        for (int mt = 0; mt < 4; ++mt)
#pragma unroll
            for (int nt = 0; nt < 2; ++nt)
                acc[mt][nt] = __builtin_amdgcn_mfma_f32_16x16x32_bf16(
                    af[mt], bfr[nt], acc[mt][nt], 0, 0, 0);
        __syncthreads();
    }
#pragma unroll
    for (int nt = 0; nt < 2; ++nt) {
        int o = wn + nt * 16 + lrow;
        float bv = bf2f(Tp[o * IP + 256]);
#pragma unroll
        for (int mt = 0; mt < 4; ++mt)
#pragma unroll
            for (int r = 0; r < 4; ++r) {
                int m = m0 + wm + mt * 16 + lq * 4 + r;
                out[((size_t)bl * 512 + m) * 64 + o] = acc[mt][nt][r] + bv;
            }
    }
}

extern "C" void kernel_launch(void* const* d_in, const int* in_sizes, int n_in,
                              void* d_out, int out_size, void* d_ws, size_t ws_size,
                              hipStream_t stream) {
    const float* x1 = (const float*)d_in[0];
    const float* x2 = (const float*)d_in[1];
    const float* U  = (const float*)d_in[2];
    float* out = (float*)d_out;

    char* ws = (char*)d_ws;
    unsigned short* x1b  = (unsigned short*)(ws);                       //  2 MiB
    unsigned short* x2b  = (unsigned short*)(ws + 2097152);             //  2 MiB
    unsigned short* W2   = (unsigned short*)(ws + 4194304);             //  8650752 B
    float*          Ubias= (float*)        (ws + 4194304 + 8650752);    //  67584 B
    unsigned short* T    = (unsigned short*)(ws + 4194304 + 8650752 + 67584); // 138412032 B

    hipLaunchKernelGGL(cvt_x, dim3(2048), dim3(256), 0, stream, x1, x2, x1b, x2b);
    hipLaunchKernelGGL(cvt_u, dim3((N1 * 64) / 256), dim3(256), 0, stream, U, W2, Ubias);
    hipLaunchKernelGGL(gemm1, dim3(N1 / 128, M1 / 128), dim3(256), 0, stream, x1b, W2, Ubias, T);
    hipLaunchKernelGGL(gemm2, dim3(L_ / 128, M1), dim3(256), 0, stream, x2b, T, out);
}